// Round 1
// baseline (75.558 us; speedup 1.0000x reference)
//
#include <hip/hip_runtime.h>

// Problem constants (from reference setup_inputs):
//   B=32, L=4096, V=10, F=1024, D=64
// out[1, b*D+d, l] = sum_f fp_table[idx[b,l], f] * W[d, f] + bias[d]
// Since V=10, precompute P[v,d] (640 floats) then pure gather.
#define B_SIZE 32
#define L_SIZE 4096
#define V_SIZE 10
#define F_SIZE 1024
#define D_SIZE 64

// Kernel 1: Pt[d*V + v] = dot(fp_table[v,:], W[d,:]) + bias[d]
// One wave (64 lanes) per (v,d) output; 640 blocks of 64 threads.
__global__ __launch_bounds__(64) void fp_proj_kernel(
    const float* __restrict__ fp_table,
    const float* __restrict__ W,
    const float* __restrict__ bias,
    float* __restrict__ Pt) {
  const int o = blockIdx.x;          // 0..639
  const int v = o / D_SIZE;          // 0..9
  const int d = o % D_SIZE;          // 0..63
  const int lane = threadIdx.x;      // 0..63

  const float4* ft4 = (const float4*)(fp_table + v * F_SIZE);
  const float4* w4  = (const float4*)(W + d * F_SIZE);

  float sum = 0.f;
  // F/4 = 256 float4 elements, 64 lanes -> 4 iterations each
  for (int i = lane; i < F_SIZE / 4; i += 64) {
    float4 a = ft4[i];
    float4 b = w4[i];
    sum += a.x * b.x + a.y * b.y + a.z * b.z + a.w * b.w;
  }
  // full-wave butterfly/shuffle reduction over 64 lanes
  #pragma unroll
  for (int off = 32; off > 0; off >>= 1)
    sum += __shfl_down(sum, off, 64);

  if (lane == 0) Pt[d * V_SIZE + v] = sum + bias[d];
}

// Kernel 2: gather. One thread per output float4.
// g indexes float4s: row r = g>>10 (L/4=1024 f4 per row), col4 = g&1023.
// r = b*64 + d. out[r*L + 4*col4 .. +3] = Pt[d*V + idx[b*L + 4*col4 + j]]
__global__ __launch_bounds__(256) void gather_kernel(
    const int* __restrict__ idx,
    const float* __restrict__ Pt,
    float* __restrict__ out) {
  __shared__ float Pl[D_SIZE * V_SIZE];  // 640 floats = 2.5 KB
  for (int i = threadIdx.x; i < D_SIZE * V_SIZE; i += 256) Pl[i] = Pt[i];
  __syncthreads();

  const int g  = blockIdx.x * 256 + threadIdx.x;  // 0 .. 2M-1
  const int r  = g >> 10;     // output row, 0..2047
  const int c4 = g & 1023;    // float4 column
  const int b  = r >> 6;      // batch
  const int d  = r & 63;      // dim

  // 4 consecutive indices for this float4 (16B-aligned int4 load)
  const int4 vi = ((const int4*)idx)[b * (L_SIZE / 4) + c4];

  // All lanes in a wave share d -> <=10 distinct LDS addresses on 10
  // consecutive banks; duplicates broadcast -> conflict-free.
  const float* Pd = Pl + d * V_SIZE;
  float4 o;
  o.x = Pd[vi.x];
  o.y = Pd[vi.y];
  o.z = Pd[vi.z];
  o.w = Pd[vi.w];

  ((float4*)out)[g] = o;  // coalesced 16B/lane store
}

extern "C" void kernel_launch(void* const* d_in, const int* in_sizes, int n_in,
                              void* d_out, int out_size, void* d_ws, size_t ws_size,
                              hipStream_t stream) {
  const int*   idx      = (const int*)d_in[0];    // [B, L] int32
  const float* fp_table = (const float*)d_in[1];  // [V, F]
  const float* W        = (const float*)d_in[2];  // [D, F]
  const float* bias     = (const float*)d_in[3];  // [D]
  float* out = (float*)d_out;                     // [1, B*D, L] fp32
  float* Pt  = (float*)d_ws;                      // [D, V] = 640 floats scratch

  // Stage 1: 640 (v,d) dot products, one wave each.
  fp_proj_kernel<<<V_SIZE * D_SIZE, 64, 0, stream>>>(fp_table, W, bias, Pt);

  // Stage 2: gather, one thread per float4 of the 32 MiB output.
  const int total4 = B_SIZE * D_SIZE * (L_SIZE / 4);  // 2,097,152
  gather_kernel<<<total4 / 256, 256, 0, stream>>>(idx, Pt, out);
}